// Round 14
// baseline (312.168 us; speedup 1.0000x reference)
//
#include <hip/hip_runtime.h>
#include <hip/hip_bf16.h>
#include <stdint.h>

// TernaryLinear: out = scale * (x_bf16 @ wq_bf16^T), scale = mean|W|+1e-8
// M=8192, K=2048, N=8192. fp32 in/out.
//
// GEMM: 128x128 tile, BK=64, 4 waves (2x2), 64KB LDS double-buffer =>
// 2 BLOCKS/CU. The two waves per SIMD belong to different blocks, so barrier
// waits / LDS drains of one block overlap the other block's MFMAs (hardware
// scheduler). Schedule = R5/R11 minimal-barrier counted-vm pipeline:
//   ph1: STAGE B(T+1)h0 | rd a0-3 (8), b01 (4) | MFMA Q(n01,kc0)
//   ph2: STAGE B(T+1)h1 | rd b23 (4)           | MFMA Q(n01,kc1) | SBAR
//   ph3: STAGE A(T+2)h0 |                      | MFMA Q(n23,kc0)
//   ph4: STAGE A(T+2)h1 |                      | MFMA Q(n23,kc1) | vm(4) SBAR
// WAR: A-stage@ph3 into CB.A: its readers (rd a @ph1) retired before their
// ph1-MFMAs; all waves passed ph2-end SBAR => safe. B-stage@ph1 into OB.B:
// OB.B's readers were prev tile's (>=1 barrier ago) => safe.
// RAW/vm ledger (2 loads per STAGE): ph4-end queue = [A(T+1)4 (prev ph3/4),
// B(T+1)4 (this ph1/2), A(T+2)4 (this ph3/4)] = 12 -> vm(4) forces
// A(T+1)+B(T+1) (exactly the next tile's reads), leaves A(T+2). Never vm(0)
// in the main loop. Prologue stages A0,B0,A1 (12 loads), vm(4) leaves A1.
// Tail: tile30 stages only B(31), vm(0) final drain; tile31 reads only.

typedef __attribute__((ext_vector_type(8))) short   s16x8;
typedef __attribute__((ext_vector_type(4))) float   f32x4;

#define K_DIM   2048
#define K2      4096        // row stride bytes (bf16)
#define N_DIM   8192
#define N4      4194304     // 8192*2048/4

// ---------------- scale reduction ----------------
__global__ void k_abs_part(const float4* __restrict__ w4, float* __restrict__ part) {
    int tid = blockIdx.x * 256 + threadIdx.x;
    float s = 0.f;
    for (int i = tid; i < N4; i += gridDim.x * 256) {
        float4 v = w4[i];
        s += fabsf(v.x) + fabsf(v.y) + fabsf(v.z) + fabsf(v.w);
    }
    for (int off = 32; off > 0; off >>= 1) s += __shfl_down(s, off, 64);
    __shared__ float tmp[4];
    int lane = threadIdx.x & 63, wid = threadIdx.x >> 6;
    if (lane == 0) tmp[wid] = s;
    __syncthreads();
    if (threadIdx.x == 0) part[blockIdx.x] = tmp[0] + tmp[1] + tmp[2] + tmp[3];
}

__global__ void k_abs_final(const float* __restrict__ part, float* __restrict__ scale) {
    float s = part[threadIdx.x] + part[threadIdx.x + 256] +
              part[threadIdx.x + 512] + part[threadIdx.x + 768];
    for (int off = 32; off > 0; off >>= 1) s += __shfl_down(s, off, 64);
    __shared__ float tmp[4];
    int lane = threadIdx.x & 63, wid = threadIdx.x >> 6;
    if (lane == 0) tmp[wid] = s;
    __syncthreads();
    if (threadIdx.x == 0) scale[0] = (tmp[0] + tmp[1] + tmp[2] + tmp[3]) / 16777216.0f + 1e-8f;
}

// ---------------- fused W-quant + X-convert ----------------
__device__ __forceinline__ uint32_t f2b(float f) {
    uint32_t u = __builtin_bit_cast(uint32_t, f);
    return (u + 0x7FFFu + ((u >> 16) & 1u)) >> 16;  // RNE
}

__global__ void k_prep(const float4* __restrict__ w4, const float4* __restrict__ x4,
                       const float* __restrict__ scale_p,
                       uint2* __restrict__ wq, uint2* __restrict__ xb) {
    int tid = (blockIdx.x & 2047) * 256 + threadIdx.x;
    if (blockIdx.x < 2048) {
        const float sc = *scale_p;
        for (int i = tid; i < N4; i += 2048 * 256) {
            float4 v = w4[i];
            float q0 = rintf(v.x / sc), q1 = rintf(v.y / sc);
            float q2 = rintf(v.z / sc), q3 = rintf(v.w / sc);
            uint32_t b0 = (q0 == 0.f) ? 0u : (q0 > 0.f ? 0x3F80u : 0xBF80u);
            uint32_t b1 = (q1 == 0.f) ? 0u : (q1 > 0.f ? 0x3F80u : 0xBF80u);
            uint32_t b2 = (q2 == 0.f) ? 0u : (q2 > 0.f ? 0x3F80u : 0xBF80u);
            uint32_t b3 = (q3 == 0.f) ? 0u : (q3 > 0.f ? 0x3F80u : 0xBF80u);
            uint2 o; o.x = b0 | (b1 << 16); o.y = b2 | (b3 << 16);
            wq[i] = o;
        }
    } else {
        for (int i = tid; i < N4; i += 2048 * 256) {
            float4 v = x4[i];
            uint2 o;
            o.x = f2b(v.x) | (f2b(v.y) << 16);
            o.y = f2b(v.z) | (f2b(v.w) << 16);
            xb[i] = o;
        }
    }
}

// ---------------- GEMM ----------------
__device__ __forceinline__ void mfma16(f32x4& c, s16x8 a, s16x8 b) {
    asm("v_mfma_f32_16x16x32_bf16 %0, %1, %2, %0" : "+v"(c) : "v"(a), "v"(b));
}
__device__ __forceinline__ void load_lds16(const void* g, void* l) {
    __builtin_amdgcn_global_load_lds(
        (const __attribute__((address_space(1))) uint32_t*)g,
        (__attribute__((address_space(3))) uint32_t*)l, 16, 0, 0);
}

#define SCHED0 __builtin_amdgcn_sched_barrier(0)
#define SBAR do { SCHED0; __builtin_amdgcn_s_barrier(); SCHED0; } while (0)
#define WAIT_VM(N) do { asm volatile("s_waitcnt vmcnt(" #N ")" ::: "memory"); SCHED0; } while (0)

// LDS byte map (64 KiB): buf0.A=0, buf0.B=16384, buf1.A=32768, buf1.B=49152
#define A0B 0
#define B0B 16384
#define A1B 32768
#define B1B 49152

__global__ __launch_bounds__(256, 2) void k_gemm(
    const unsigned short* __restrict__ Xb,
    const unsigned short* __restrict__ Wb,
    const float* __restrict__ scale_p,
    float* __restrict__ out)
{
    extern __shared__ uint8_t smem[];
    const int tid  = threadIdx.x;
    const int lane = tid & 63;
    const int wid  = tid >> 6;          // 0..3
    const int wr   = wid >> 1;          // 0..1
    const int wc   = wid & 1;           // 0..1

    // XCD-supertiled mapping (bijective: 4096 = 8 XCD x 512; XCD owns 8 rows).
    // Concurrent ~64 blocks/XCD = 8 rows x 8 cols supertile.
    const int bid = blockIdx.x;
    const int xcd = bid & 7;
    const int l   = bid >> 3;                 // 0..511
    const int tileRow = xcd * 8 + (l & 7);    // 0..63
    const int tileCol = l >> 3;               // 0..63

    const uint8_t* gA = (const uint8_t*)Xb + (size_t)tileRow * 128 * K2;
    const uint8_t* gB = (const uint8_t*)Wb + (size_t)tileCol * 128 * K2;

    // staging: one STAGE = 2 gload_lds x 4 waves = 8KB = 64 rows x 64 cols.
    // thread t covers rows (t>>3) and (t>>3)+32; slot t&7. Physical LDS slot c
    // of row r holds global col-slot (c ^ (r&7)) (XOR swizzle). (r+32)&7==r&7,
    // so the second call's source is just +32*K2.
    const int srow = tid >> 3, sslot = tid & 7;
    const size_t srcOff = (size_t)srow * K2 + (size_t)((sslot ^ (srow & 7)) * 16);
    const uint8_t* gAs = gA + srcOff;
    const uint8_t* gBs = gB + srcOff;
    const int dstOff = tid * 16;

    // LDS read bases; frag m adds m*2048 (16 rows * 128B)
    const int rA = wr * 64 + (lane & 15);
    const int rB = wc * 64 + (lane & 15);
    const int h  = lane >> 4;
    const int pA0 = rA * 128 + (((h    ) ^ (rA & 7)) * 16);
    const int pA1 = rA * 128 + (((4 + h) ^ (rA & 7)) * 16);
    const int pB0 = rB * 128 + (((h    ) ^ (rB & 7)) * 16);
    const int pB1 = rB * 128 + (((4 + h) ^ (rB & 7)) * 16);

    s16x8 a[4][2], b[4][2];
    f32x4 acc[4][4];
    #pragma unroll
    for (int m = 0; m < 4; ++m)
        #pragma unroll
        for (int n = 0; n < 4; ++n) acc[m][n] = (f32x4){0.f, 0.f, 0.f, 0.f};

#define LD8(OFF) (*(const s16x8*)(smem + (OFF)))
// STAGE: 8KB = rows [R0, R0+63] of a region half. BOFF selects k-offset (+ row
// base): h0 = BOFF, h1 = BOFF + 262144 (row 64).
#define STAGE(LBASE, GP, BOFF) do { \
    load_lds16((GP) + (BOFF),          smem + (LBASE) + dstOff); \
    load_lds16((GP) + (BOFF) + 131072, smem + (LBASE) + 4096 + dstOff); \
    SCHED0; } while (0)

#define RD_A(AB) do { _Pragma("unroll") for (int m = 0; m < 4; ++m) { \
    a[m][0] = LD8((AB) + pA0 + m * 2048); a[m][1] = LD8((AB) + pA1 + m * 2048); } } while (0)
#define RD_B01(BB) do { _Pragma("unroll") for (int n = 0; n < 2; ++n) { \
    b[n][0] = LD8((BB) + pB0 + n * 2048); b[n][1] = LD8((BB) + pB1 + n * 2048); } } while (0)
#define RD_B23(BB) do { _Pragma("unroll") for (int n = 2; n < 4; ++n) { \
    b[n][0] = LD8((BB) + pB0 + n * 2048); b[n][1] = LD8((BB) + pB1 + n * 2048); } } while (0)

// 8 MFMA: all m, n in [NLO, NLO+1], one kc
#define MFMA_Q(NLO, KC) do { \
    __builtin_amdgcn_s_setprio(1); \
    _Pragma("unroll") for (int m = 0; m < 4; ++m) \
        _Pragma("unroll") for (int n = 0; n < 2; ++n) \
            mfma16(acc[m][(NLO) + n], a[m][(KC)], b[(NLO) + n][(KC)]); \
    __builtin_amdgcn_s_setprio(0); \
    SCHED0; } while (0)

    // prologue: A(0),B(0)->buf0, A(1)->buf1.A (12 loads); vm(4) forces A0,B0,
    // leaves A1 in flight (steady-state entry).
    STAGE(A0B, gAs, 0);   STAGE(A0B + 8192, gAs, 262144);
    STAGE(B0B, gBs, 0);   STAGE(B0B + 8192, gBs, 262144);
    STAGE(A1B, gAs, 128); STAGE(A1B + 8192, gAs, 262144 + 128);
    WAIT_VM(4);
    SBAR;

    #pragma unroll 1
    for (int i = 0; i < 15; ++i) {
        const int kb1 = (2 * i + 1) * 128;   // T+1
        const int kb2 = kb1 + 128;           // T+2
        const int kb3 = kb1 + 256;           // T+3
        // ---- even tile T on buf0 ----
        // ph1
        STAGE(B1B, gBs, kb1);
        RD_A(A0B); RD_B01(B0B);
        MFMA_Q(0, 0);
        // ph2
        STAGE(B1B + 8192, gBs, 262144 + kb1);
        RD_B23(B0B);
        MFMA_Q(0, 1);
        SBAR;                                   // buf0.A dead
        // ph3
        STAGE(A0B, gAs, kb2);
        MFMA_Q(2, 0);
        // ph4
        STAGE(A0B + 8192, gAs, 262144 + kb2);
        MFMA_Q(2, 1);
        WAIT_VM(4); SBAR;                       // A(T+1),B(T+1) landed; buf0.B dead
        // ---- odd tile T+1 on buf1 ----
        // ph1
        STAGE(B0B, gBs, kb2);
        RD_A(A1B); RD_B01(B1B);
        MFMA_Q(0, 0);
        // ph2
        STAGE(B0B + 8192, gBs, 262144 + kb2);
        RD_B23(B1B);
        MFMA_Q(0, 1);
        SBAR;                                   // buf1.A dead
        // ph3
        STAGE(A1B, gAs, kb3);
        MFMA_Q(2, 0);
        // ph4
        STAGE(A1B + 8192, gAs, 262144 + kb3);
        MFMA_Q(2, 1);
        WAIT_VM(4); SBAR;                       // A(T+2),B(T+2) landed; buf1.B dead
    }

    // tail: tile 30 (buf0; stages only B(31), vm(0) drain), tile 31 (buf1)
    {
        const int kb1 = 31 * 128;
        STAGE(B1B, gBs, kb1);
        RD_A(A0B); RD_B01(B0B);
        MFMA_Q(0, 0);
        STAGE(B1B + 8192, gBs, 262144 + kb1);
        RD_B23(B0B);
        MFMA_Q(0, 1);
        SBAR;
        MFMA_Q(2, 0);
        MFMA_Q(2, 1);
        WAIT_VM(0); SBAR;                       // A(31),B(31) landed
        RD_A(A1B); RD_B01(B1B);
        MFMA_Q(0, 0);
        RD_B23(B1B);
        MFMA_Q(0, 1);
        MFMA_Q(2, 0);
        MFMA_Q(2, 1);
    }

    // epilogue: C[row][col], col=lane&15, row=(lane>>4)*4+j (verified mapping)
    const float sc = *scale_p;
    const int orow0 = tileRow * 128 + wr * 64 + ((lane >> 4) << 2);
    const int ocol0 = tileCol * 128 + wc * 64 + (lane & 15);
    #pragma unroll
    for (int m = 0; m < 4; ++m)
        #pragma unroll
        for (int n = 0; n < 4; ++n)
            #pragma unroll
            for (int j = 0; j < 4; ++j)
                out[(size_t)(orow0 + m * 16 + j) * N_DIM + (ocol0 + n * 16)] = acc[m][n][j] * sc;

#undef LD8
#undef STAGE
#undef RD_A
#undef RD_B01
#undef RD_B23
#undef MFMA_Q
}

// ---------------- launch ----------------
extern "C" void kernel_launch(void* const* d_in, const int* in_sizes, int n_in,
                              void* d_out, int out_size, void* d_ws, size_t ws_size,
                              hipStream_t stream) {
    const float* x = (const float*)d_in[0];
    const float* w = (const float*)d_in[1];
    float* out = (float*)d_out;
    uint8_t* ws = (uint8_t*)d_ws;

    float* part  = (float*)ws;                       // 1024 floats
    float* scale = (float*)(ws + 4096);              // 1 float
    unsigned short* Xb = (unsigned short*)(ws + 8192);
    unsigned short* Wb = (unsigned short*)(ws + 8192 + 33554432ull);

    (void)hipFuncSetAttribute((const void*)k_gemm,
                              hipFuncAttributeMaxDynamicSharedMemorySize, 65536);

    hipLaunchKernelGGL(k_abs_part, dim3(1024), dim3(256), 0, stream, (const float4*)w, part);
    hipLaunchKernelGGL(k_abs_final, dim3(1), dim3(256), 0, stream, part, scale);
    hipLaunchKernelGGL(k_prep, dim3(4096), dim3(256), 0, stream,
                       (const float4*)w, (const float4*)x, scale, (uint2*)Wb, (uint2*)Xb);
    hipLaunchKernelGGL(k_gemm, dim3(4096), dim3(256), 65536, stream, Xb, Wb, scale, out);
}